// Round 5
// baseline (798.928 us; speedup 1.0000x reference)
//
#include <hip/hip_runtime.h>

// Problem constants (from reference)
#define B_TREES 32
#define DEPTH   12
#define M_NODES 4095                  // 2^12 - 1
#define N_NODES (B_TREES * M_NODES)   // 131040
#define HDIM    256
#define VOCAB   32000
#define NCLS    20
#define LEAFROWS 65536                // 32 * 2048 leaves
#define LDS_STRIDE 68                 // 16-row per-wave tile stride (f16/f32)

typedef _Float16 f16;
typedef _Float16 f16x8 __attribute__((ext_vector_type(8)));
typedef _Float16 f16x4 __attribute__((ext_vector_type(4)));
typedef float    f32x4 __attribute__((ext_vector_type(4)));

__device__ __forceinline__ float sigf(float x)      { return 1.0f / (1.0f + __expf(-x)); }
__device__ __forceinline__ float tanh_fast(float x) { return 1.0f - 2.0f / (1.0f + __expf(2.0f * x)); }

// ---------------------------------------------------------------------------
// Init: convert Emb + weights to fp16. W_out padded to 32 rows (zeros).
// ---------------------------------------------------------------------------
__global__ __launch_bounds__(256) void cvt_kernel(
    const float4* __restrict__ Emb,  const float4* __restrict__ Wiou,
    const float4* __restrict__ Uiou, const float4* __restrict__ Uf,
    const float4* __restrict__ Wout,
    f16x4* __restrict__ Emb16,  f16x4* __restrict__ Wiou16,
    f16x4* __restrict__ Uiou16, f16x4* __restrict__ Uf16,
    f16x4* __restrict__ Wout16)
{
    int i = blockIdx.x * 256 + threadIdx.x;   // in units of 4 floats
    if (i < VOCAB * HDIM / 4) {
        float4 v = Emb[i];
        f16x4 r; r[0] = (f16)v.x; r[1] = (f16)v.y; r[2] = (f16)v.z; r[3] = (f16)v.w;
        Emb16[i] = r;
    }
    if (i < 768 * HDIM / 4) {
        float4 v = Wiou[i];
        f16x4 r; r[0] = (f16)v.x; r[1] = (f16)v.y; r[2] = (f16)v.z; r[3] = (f16)v.w;
        Wiou16[i] = r;
        float4 u = Uiou[i];
        f16x4 s; s[0] = (f16)u.x; s[1] = (f16)u.y; s[2] = (f16)u.z; s[3] = (f16)u.w;
        Uiou16[i] = s;
    }
    if (i < HDIM * HDIM / 4) {
        float4 v = Uf[i];
        f16x4 r; r[0] = (f16)v.x; r[1] = (f16)v.y; r[2] = (f16)v.z; r[3] = (f16)v.w;
        Uf16[i] = r;
    }
    if (i < 32 * HDIM / 4) {                  // 32 padded rows of W_out
        int row = i >> 6;
        f16x4 r = {};
        if (row < NCLS) {
            float4 v = Wout[i];
            r[0] = (f16)v.x; r[1] = (f16)v.y; r[2] = (f16)v.z; r[3] = (f16)v.w;
        }
        Wout16[i] = r;
    }
}

// ---------------------------------------------------------------------------
// Leaf kernel: xiou = Emb16[x] @ Wiou16^T (+b_iou), fused gate epilogue.
// Grid (1024, 4): 64 rows x 64 cols per block, 16x64 per wave. No block
// barriers — h transposed through a per-wave LDS tile (wave-synchronous).
// ---------------------------------------------------------------------------
__global__ __launch_bounds__(256) void leaf_kernel(
    const int* __restrict__ x, const f16* __restrict__ Emb16,
    const f16* __restrict__ Wiou16, const float* __restrict__ b_iou,
    f16* __restrict__ h16, f16* __restrict__ cT)
{
    __shared__ f16 ldsh[4][16 * LDS_STRIDE];   // 8.7 KB, per-wave slices

    const int lane = threadIdx.x & 63;
    const int w    = threadIdx.x >> 6;
    const int quad = lane >> 4;
    const int l15  = lane & 15;
    const int qk   = quad * 8;
    const int rw   = blockIdx.x * 64 + w * 16;    // wave's first leaf row
    const int cb0  = blockIdx.y * 64;

    // rows rw..rw+15 lie in one tree (16 | 2048): contiguous nodes
    const int nodeRow = (rw >> 11) * M_NODES + 2047 + (rw & 2047);
    const int embBase = x[nodeRow + l15] * HDIM;

    f16x8 a[8];
    #pragma unroll
    for (int ks = 0; ks < 8; ++ks)
        a[ks] = *(const f16x8*)(Emb16 + embBase + ks * 32 + qk);

    f32x4 acc[3][4] = {};
    #pragma unroll
    for (int ks = 0; ks < 8; ++ks) {
        const int k0 = ks * 32 + qk;
        #pragma unroll
        for (int mat = 0; mat < 3; ++mat) {
            f16x8 bf[4];
            #pragma unroll
            for (int cf = 0; cf < 4; ++cf)
                bf[cf] = *(const f16x8*)(Wiou16 +
                    (mat * 256 + cb0 + cf * 16 + l15) * HDIM + k0);
            #pragma unroll
            for (int cf = 0; cf < 4; ++cf)
                acc[mat][cf] = __builtin_amdgcn_mfma_f32_16x16x32_f16(
                    a[ks], bf[cf], acc[mat][cf], 0, 0, 0);
        }
    }

    // Epilogue: leaves have h_sum = 0, fc_sum = 0.
    const int rloc = quad * 4;
    #pragma unroll
    for (int cf = 0; cf < 4; ++cf) {
        const int col = cb0 + cf * 16 + l15;
        const float bi = b_iou[col], bo = b_iou[256 + col], bu = b_iou[512 + col];
        f16x4 cv;
        #pragma unroll
        for (int r = 0; r < 4; ++r) {
            float i_ = acc[0][cf][r] + bi;
            float o_ = acc[1][cf][r] + bo;
            float u_ = acc[2][cf][r] + bu;
            float c  = sigf(i_) * tanh_fast(u_);
            float h  = sigf(o_) * tanh_fast(c);
            cv[r] = (f16)c;
            ldsh[w][(rloc + r) * LDS_STRIDE + cf * 16 + l15] = (f16)h;
        }
        *(f16x4*)(cT + col * LEAFROWS + rw + rloc) = cv;
    }
    // Wave-local drain: 16 rows x 64 cols -> coalesced 16B stores
    #pragma unroll
    for (int t = 0; t < 2; ++t) {
        int idx   = lane + t * 64;
        int row_l = idx >> 3, chunk = idx & 7;
        f16x8 v = *(const f16x8*)(&ldsh[w][row_l * LDS_STRIDE + chunk * 8]);
        *(f16x8*)(h16 + (nodeRow + row_l) * HDIM + cb0 + chunk * 8) = v;
    }
}

// ---------------------------------------------------------------------------
// Fused level kernel (parent level l): 64 parents x 64 cols per block,
// 16 parents (32 children) per wave. Phase 1: forget gates on the wave's 32
// children, fc pair-sum -> per-wave LDS (exactly the 16 parents this wave
// needs in phase 2 — no block barrier). Phase 2: iou GEMM on child-sum h.
// ---------------------------------------------------------------------------
__global__ __launch_bounds__(256) void fused_level_kernel(
    const f16* __restrict__ Uiou16, const f16* __restrict__ Uf16,
    const float* __restrict__ b_iou, const float* __restrict__ b_f,
    f16* __restrict__ h16, const f16* __restrict__ cT_child,
    f16* __restrict__ cT_parent, int l, int rows_p)
{
    __shared__ float fcs[4][16 * LDS_STRIDE];   // 17.4 KB
    __shared__ f16  ldsh[4][16 * LDS_STRIDE];   //  8.7 KB

    const int lane = threadIdx.x & 63;
    const int w    = threadIdx.x >> 6;
    const int quad = lane >> 4;
    const int l15  = lane & 15;
    const int qk   = quad * 8;
    const int cb0  = blockIdx.y * 64;
    const int lc   = l + 1;
    const int maskc = (1 << lc) - 1;
    const int maskp = (1 << l) - 1;
    const int rows_c = rows_p * 2;

    const int pw_raw = blockIdx.x * 64 + w * 16;     // wave's first parent
    const bool waveValid = (pw_raw < rows_p);
    const int pw = waveValid ? pw_raw : (rows_p - 16);
    const int cw = 2 * pw;                           // wave's first child row

    // ---------------- Phase 1: forget gates on 32 children ----------------
    {
        f16x4 cc[2][4];
        #pragma unroll
        for (int rf = 0; rf < 2; ++rf)
            #pragma unroll
            for (int cf = 0; cf < 4; ++cf)
                cc[rf][cf] = *(const f16x4*)(cT_child +
                    (cb0 + cf * 16 + l15) * rows_c + cw + rf * 16 + quad * 4);

        int childBase[2];
        #pragma unroll
        for (int rf = 0; rf < 2; ++rf) {
            int cl = cw + rf * 16 + l15;
            childBase[rf] = ((cl >> lc) * M_NODES + maskc + (cl & maskc)) * HDIM;
        }

        f32x4 accf[2][4] = {};
        #pragma unroll
        for (int ks = 0; ks < 8; ++ks) {
            const int k0 = ks * 32 + qk;
            f16x8 a0 = *(const f16x8*)(h16 + childBase[0] + k0);
            f16x8 a1 = *(const f16x8*)(h16 + childBase[1] + k0);
            f16x8 bf[4];
            #pragma unroll
            for (int cf = 0; cf < 4; ++cf)
                bf[cf] = *(const f16x8*)(Uf16 + (cb0 + cf * 16 + l15) * HDIM + k0);
            #pragma unroll
            for (int cf = 0; cf < 4; ++cf) {
                accf[0][cf] = __builtin_amdgcn_mfma_f32_16x16x32_f16(
                    a0, bf[cf], accf[0][cf], 0, 0, 0);
                accf[1][cf] = __builtin_amdgcn_mfma_f32_16x16x32_f16(
                    a1, bf[cf], accf[1][cf], 0, 0, 0);
            }
        }

        // fc pair-sum: child local rows rf*16+quad*4+{0..3} -> parent local
        // rf*8 + quad*2 + {0,1}; same lane holds both children of a pair.
        #pragma unroll
        for (int rf = 0; rf < 2; ++rf) {
            #pragma unroll
            for (int cf = 0; cf < 4; ++cf) {
                const float bfv = b_f[cb0 + cf * 16 + l15];
                #pragma unroll
                for (int pr = 0; pr < 2; ++pr) {
                    float f0 = sigf(accf[rf][cf][2 * pr]     + bfv);
                    float f1 = sigf(accf[rf][cf][2 * pr + 1] + bfv);
                    float fc = f0 * (float)cc[rf][cf][2 * pr]
                             + f1 * (float)cc[rf][cf][2 * pr + 1];
                    fcs[w][(rf * 8 + quad * 2 + pr) * LDS_STRIDE
                           + cf * 16 + l15] = fc;
                }
            }
        }
    }

    // ---------------- Phase 2: iou GEMM on child-sum h ----------------
    int pcBase;
    {
        int p = pw + l15;
        int b = p >> l, t = p & maskp;
        pcBase = (b * M_NODES + (2 << l) - 1 + 2 * t) * HDIM;
    }

    f32x4 acc[3][4] = {};
    #pragma unroll
    for (int ks = 0; ks < 8; ++ks) {
        const int k0 = ks * 32 + qk;
        f16x8 a1 = *(const f16x8*)(h16 + pcBase + k0);
        f16x8 a2 = *(const f16x8*)(h16 + pcBase + HDIM + k0);
        f16x8 a  = a1 + a2;                           // child-sum of h
        #pragma unroll
        for (int mat = 0; mat < 3; ++mat) {
            f16x8 bf[4];
            #pragma unroll
            for (int cf = 0; cf < 4; ++cf)
                bf[cf] = *(const f16x8*)(Uiou16 +
                    (mat * 256 + cb0 + cf * 16 + l15) * HDIM + k0);
            #pragma unroll
            for (int cf = 0; cf < 4; ++cf)
                acc[mat][cf] = __builtin_amdgcn_mfma_f32_16x16x32_f16(
                    a, bf[cf], acc[mat][cf], 0, 0, 0);
        }
    }

    const int rloc = quad * 4;
    #pragma unroll
    for (int cf = 0; cf < 4; ++cf) {
        const int col = cb0 + cf * 16 + l15;
        const float bi = b_iou[col], bo = b_iou[256 + col], bu = b_iou[512 + col];
        f16x4 cv;
        #pragma unroll
        for (int r = 0; r < 4; ++r) {
            float fcv = fcs[w][(rloc + r) * LDS_STRIDE + cf * 16 + l15];
            float i_ = acc[0][cf][r] + bi;
            float o_ = acc[1][cf][r] + bo;
            float u_ = acc[2][cf][r] + bu;
            float c  = sigf(i_) * tanh_fast(u_) + fcv;
            float h  = sigf(o_) * tanh_fast(c);
            cv[r] = (f16)c;
            ldsh[w][(rloc + r) * LDS_STRIDE + cf * 16 + l15] = (f16)h;
        }
        if (waveValid)
            *(f16x4*)(cT_parent + col * rows_p + pw + rloc) = cv;
    }
    // Wave-local drain of h (node index recomputed per row: trees may be
    // shorter than 16 rows at deep levels)
    if (waveValid) {
        #pragma unroll
        for (int t = 0; t < 2; ++t) {
            int idx   = lane + t * 64;
            int row_l = idx >> 3, chunk = idx & 7;
            int p  = pw + row_l;
            int b  = p >> l, tt = p & maskp;
            int node = b * M_NODES + (1 << l) - 1 + tt;
            f16x8 v = *(const f16x8*)(&ldsh[w][row_l * LDS_STRIDE + chunk * 8]);
            *(f16x8*)(h16 + node * HDIM + cb0 + chunk * 8) = v;
        }
    }
}

// ---------------------------------------------------------------------------
// Output: out = h_all @ W_out^T + b_out, MFMA with N padded 20->32.
// ---------------------------------------------------------------------------
__global__ __launch_bounds__(256) void out_kernel(
    const f16* __restrict__ h16, const f16* __restrict__ Wout16,
    const float* __restrict__ bout, float* __restrict__ out)
{
    const int lane = threadIdx.x & 63;
    const int w    = threadIdx.x >> 6;
    const int quad = lane >> 4;
    const int r0   = blockIdx.x * 128;
    const int qk   = quad * 8;
    const int l15  = lane & 15;

    int rowBase[2];
    #pragma unroll
    for (int rf = 0; rf < 2; ++rf) {
        int row = r0 + w * 32 + rf * 16 + l15;
        if (row >= N_NODES) row = N_NODES - 1;
        rowBase[rf] = row * HDIM;
    }
    int wB[2];
    #pragma unroll
    for (int cf = 0; cf < 2; ++cf)
        wB[cf] = (cf * 16 + l15) * HDIM;

    f32x4 acc[2][2] = {};
    #pragma unroll
    for (int ks = 0; ks < 8; ++ks) {
        const int k0 = ks * 32 + qk;
        f16x8 a[2], bf[2];
        #pragma unroll
        for (int rf = 0; rf < 2; ++rf)
            a[rf] = *(const f16x8*)(h16 + rowBase[rf] + k0);
        #pragma unroll
        for (int cf = 0; cf < 2; ++cf)
            bf[cf] = *(const f16x8*)(Wout16 + wB[cf] + k0);
        #pragma unroll
        for (int rf = 0; rf < 2; ++rf)
            #pragma unroll
            for (int cf = 0; cf < 2; ++cf)
                acc[rf][cf] = __builtin_amdgcn_mfma_f32_16x16x32_f16(
                    a[rf], bf[cf], acc[rf][cf], 0, 0, 0);
    }

    #pragma unroll
    for (int rf = 0; rf < 2; ++rf) {
        const int rbase = r0 + w * 32 + rf * 16 + quad * 4;
        #pragma unroll
        for (int cf = 0; cf < 2; ++cf) {
            const int col = cf * 16 + l15;
            if (col < NCLS) {
                const float bo = bout[col];
                #pragma unroll
                for (int r = 0; r < 4; ++r) {
                    int row = rbase + r;
                    if (row < N_NODES)
                        out[row * NCLS + col] = acc[rf][cf][r] + bo;
                }
            }
        }
    }
}

// ---------------------------------------------------------------------------
extern "C" void kernel_launch(void* const* d_in, const int* in_sizes, int n_in,
                              void* d_out, int out_size, void* d_ws, size_t ws_size,
                              hipStream_t stream)
{
    const int*   x     = (const int*)d_in[0];
    // d_in[1] = x_mask: leaf structure is static — folded into indexing.
    const float* Emb   = (const float*)d_in[2];
    const float* W_iou = (const float*)d_in[3];
    const float* b_iou = (const float*)d_in[4];
    const float* U_iou = (const float*)d_in[5];
    const float* U_f   = (const float*)d_in[6];
    const float* b_f   = (const float*)d_in[7];
    const float* W_out = (const float*)d_in[8];
    const float* b_out = (const float*)d_in[9];
    float* out = (float*)d_out;

    // Workspace: h16 67.1 + cA 33.6 + cB 16.8 + Emb16 16.4 + weights ~1 MB
    // = ~135 MB (round-2's 202 MB fit, so safe).
    char* ws = (char*)d_ws;
    size_t off = 0;
    auto take = [&](size_t bytes) -> char* {
        char* p = ws + off; off += (bytes + 255) & ~(size_t)255; return p;
    };
    f16* h16    = (f16*)take((size_t)N_NODES * HDIM * 2);
    f16* cA     = (f16*)take((size_t)HDIM * LEAFROWS * 2);        // [256][65536]
    f16* cB     = (f16*)take((size_t)HDIM * (LEAFROWS / 2) * 2);  // [256][32768]
    f16* Emb16  = (f16*)take((size_t)VOCAB * HDIM * 2);
    f16* Wiou16 = (f16*)take((size_t)768 * HDIM * 2);
    f16* Uiou16 = (f16*)take((size_t)768 * HDIM * 2);
    f16* Uf16   = (f16*)take((size_t)HDIM * HDIM * 2);
    f16* Wout16 = (f16*)take((size_t)32 * HDIM * 2);

    cvt_kernel<<<VOCAB * HDIM / 4 / 256, 256, 0, stream>>>(
        (const float4*)Emb, (const float4*)W_iou, (const float4*)U_iou,
        (const float4*)U_f, (const float4*)W_out,
        (f16x4*)Emb16, (f16x4*)Wiou16, (f16x4*)Uiou16, (f16x4*)Uf16,
        (f16x4*)Wout16);

    // Leaves (level 11): 65536 rows, cT -> cA (stride 65536)
    leaf_kernel<<<dim3(1024, 4), 256, 0, stream>>>(
        x, Emb16, Wiou16, b_iou, h16, cA);

    // Levels 10..0, fused fgate+level, ping-pong transposed c buffers
    f16* cin  = cA;
    f16* cout_ = cB;
    for (int l = 10; l >= 0; --l) {
        int rows_p = B_TREES << l;
        fused_level_kernel<<<dim3((rows_p + 63) / 64, 4), 256, 0, stream>>>(
            Uiou16, Uf16, b_iou, b_f, h16, cin, cout_, l, rows_p);
        f16* t = cin; cin = cout_; cout_ = t;
    }

    out_kernel<<<dim3((N_NODES + 127) / 128), 256, 0, stream>>>(
        h16, Wout16, b_out, out);
}

// Round 6
// 564.325 us; speedup vs baseline: 1.4157x; 1.4157x over previous
//
#include <hip/hip_runtime.h>

// Problem constants (from reference)
#define B_TREES 32
#define DEPTH   12
#define M_NODES 4095                  // 2^12 - 1
#define N_NODES (B_TREES * M_NODES)   // 131040
#define HDIM    256
#define VOCAB   32000
#define NCLS    20
#define LEAFROWS 65536                // 32 * 2048 leaves

typedef _Float16 f16;
typedef _Float16 f16x8 __attribute__((ext_vector_type(8)));
typedef _Float16 f16x4 __attribute__((ext_vector_type(4)));
typedef float    f32x4 __attribute__((ext_vector_type(4)));

__device__ __forceinline__ float sigf(float x)      { return 1.0f / (1.0f + __expf(-x)); }
__device__ __forceinline__ float tanh_fast(float x) { return 1.0f - 2.0f / (1.0f + __expf(2.0f * x)); }

// ---------------------------------------------------------------------------
// Init: convert Emb + weights to fp16. W_out padded to 32 rows (zeros).
// ---------------------------------------------------------------------------
__global__ __launch_bounds__(256) void cvt_kernel(
    const float4* __restrict__ Emb,  const float4* __restrict__ Wiou,
    const float4* __restrict__ Uiou, const float4* __restrict__ Uf,
    const float4* __restrict__ Wout,
    f16x4* __restrict__ Emb16,  f16x4* __restrict__ Wiou16,
    f16x4* __restrict__ Uiou16, f16x4* __restrict__ Uf16,
    f16x4* __restrict__ Wout16)
{
    int i = blockIdx.x * 256 + threadIdx.x;   // in units of 4 floats
    if (i < VOCAB * HDIM / 4) {
        float4 v = Emb[i];
        f16x4 r; r[0] = (f16)v.x; r[1] = (f16)v.y; r[2] = (f16)v.z; r[3] = (f16)v.w;
        Emb16[i] = r;
    }
    if (i < 768 * HDIM / 4) {
        float4 v = Wiou[i];
        f16x4 r; r[0] = (f16)v.x; r[1] = (f16)v.y; r[2] = (f16)v.z; r[3] = (f16)v.w;
        Wiou16[i] = r;
        float4 u = Uiou[i];
        f16x4 s; s[0] = (f16)u.x; s[1] = (f16)u.y; s[2] = (f16)u.z; s[3] = (f16)u.w;
        Uiou16[i] = s;
    }
    if (i < HDIM * HDIM / 4) {
        float4 v = Uf[i];
        f16x4 r; r[0] = (f16)v.x; r[1] = (f16)v.y; r[2] = (f16)v.z; r[3] = (f16)v.w;
        Uf16[i] = r;
    }
    if (i < 32 * HDIM / 4) {                  // 32 padded rows of W_out
        int row = i >> 6;
        f16x4 r = {};
        if (row < NCLS) {
            float4 v = Wout[i];
            r[0] = (f16)v.x; r[1] = (f16)v.y; r[2] = (f16)v.z; r[3] = (f16)v.w;
        }
        Wout16[i] = r;
    }
}

// ---------------------------------------------------------------------------
// Leaf kernel: persistent-weight GEMM. Wave owns 16 cols x 3 gates (weights
// in 96 VGPRs, loaded once); loops 16 row-tiles of 16 rows with 1-deep
// A-prefetch. Grid (256, 4): block = 256 rows x 64 cols.
// ---------------------------------------------------------------------------
#define LEAF_CHUNK 256
#define LDSH_S 20        // f16 stride of 16x16 h transpose tile (8B-aligned)
#define FCS_S  20        // f32 stride of fcs tile
__global__ __launch_bounds__(256, 2) void leaf_kernel(
    const int* __restrict__ x, const f16* __restrict__ Emb16,
    const f16* __restrict__ Wiou16, const float* __restrict__ b_iou,
    f16* __restrict__ h16, f16* __restrict__ cT)
{
    __shared__ f16 ldsh[4][16 * LDSH_S];

    const int lane = threadIdx.x & 63;
    const int w    = threadIdx.x >> 6;
    const int quad = lane >> 4;
    const int l15  = lane & 15;
    const int qk   = quad * 8;
    const int wcol = blockIdx.y * 64 + w * 16;      // wave's 16 cols

    // Persistent weight fragments (96 VGPRs)
    f16x8 wf[3][8];
    #pragma unroll
    for (int mat = 0; mat < 3; ++mat)
        #pragma unroll
        for (int ks = 0; ks < 8; ++ks)
            wf[mat][ks] = *(const f16x8*)(Wiou16 +
                (mat * 256 + wcol + l15) * HDIM + ks * 32 + qk);
    const float bi = b_iou[wcol + l15];
    const float bo = b_iou[256 + wcol + l15];
    const float bu = b_iou[512 + wcol + l15];

    const int row0 = blockIdx.x * LEAF_CHUNK;

    // Prefetch tile 0
    int nodeRow = (row0 >> 11) * M_NODES + 2047 + (row0 & 2047);
    int embBase = x[nodeRow + l15] * HDIM;
    f16x8 a[8];
    #pragma unroll
    for (int ks = 0; ks < 8; ++ks)
        a[ks] = *(const f16x8*)(Emb16 + embBase + ks * 32 + qk);

    for (int rt = 0; rt < LEAF_CHUNK / 16; ++rt) {
        const int rw = row0 + rt * 16;
        const int curNode = nodeRow;
        f16x8 ac[8];
        #pragma unroll
        for (int ks = 0; ks < 8; ++ks) ac[ks] = a[ks];

        if (rt + 1 < LEAF_CHUNK / 16) {           // prefetch next tile
            const int rwn = rw + 16;
            nodeRow = (rwn >> 11) * M_NODES + 2047 + (rwn & 2047);
            embBase = x[nodeRow + l15] * HDIM;
            #pragma unroll
            for (int ks = 0; ks < 8; ++ks)
                a[ks] = *(const f16x8*)(Emb16 + embBase + ks * 32 + qk);
        }

        f32x4 acc[3] = {};
        #pragma unroll
        for (int ks = 0; ks < 8; ++ks)
            #pragma unroll
            for (int mat = 0; mat < 3; ++mat)
                acc[mat] = __builtin_amdgcn_mfma_f32_16x16x32_f16(
                    ac[ks], wf[mat][ks], acc[mat], 0, 0, 0);

        // Epilogue (leaves: h_sum = fc_sum = 0)
        f16x4 cv;
        #pragma unroll
        for (int r = 0; r < 4; ++r) {
            float i_ = acc[0][r] + bi;
            float o_ = acc[1][r] + bo;
            float u_ = acc[2][r] + bu;
            float c  = sigf(i_) * tanh_fast(u_);
            float h  = sigf(o_) * tanh_fast(c);
            cv[r] = (f16)c;
            ldsh[w][(quad * 4 + r) * LDSH_S + l15] = (f16)h;
        }
        *(f16x4*)(cT + (wcol + l15) * LEAFROWS + rw + quad * 4) = cv;

        // Wave-local drain of the 16x16 h tile (8B stores)
        {
            int row_l = lane >> 2, cpos = (lane & 3) * 4;
            f16x4 v = *(const f16x4*)(&ldsh[w][row_l * LDSH_S + cpos]);
            *(f16x4*)(h16 + (curNode + row_l) * HDIM + wcol + cpos) = v;
        }
    }
}

// ---------------------------------------------------------------------------
// Fused level kernel: persistent weights (Uf 32 + Uiou 96 VGPRs). Wave owns
// 16 cols; loops over 16-parent tiles: phase 1 = forget gates on the tile's
// 32 children (fc pair-sum in-lane -> per-wave LDS), phase 2 = iou GEMM on
// child-sum h + gate epilogue. No block barriers.
// ---------------------------------------------------------------------------
__global__ __launch_bounds__(256, 2) void fused_level_kernel(
    const f16* __restrict__ Uiou16, const f16* __restrict__ Uf16,
    const float* __restrict__ b_iou, const float* __restrict__ b_f,
    f16* __restrict__ h16, const f16* __restrict__ cT_child,
    f16* __restrict__ cT_parent, int l, int rows_p, int chunk)
{
    __shared__ float fcs[4][16 * FCS_S];
    __shared__ f16  ldsh[4][16 * LDSH_S];

    const int lane = threadIdx.x & 63;
    const int w    = threadIdx.x >> 6;
    const int quad = lane >> 4;
    const int l15  = lane & 15;
    const int qk   = quad * 8;
    const int wcol = blockIdx.y * 64 + w * 16;
    const int lc   = l + 1;
    const int maskc = (1 << lc) - 1;
    const int maskp = (1 << l) - 1;
    const int rows_c = rows_p * 2;

    // Persistent weight fragments
    f16x8 wfF[8], wfU[3][8];
    #pragma unroll
    for (int ks = 0; ks < 8; ++ks)
        wfF[ks] = *(const f16x8*)(Uf16 + (wcol + l15) * HDIM + ks * 32 + qk);
    #pragma unroll
    for (int mat = 0; mat < 3; ++mat)
        #pragma unroll
        for (int ks = 0; ks < 8; ++ks)
            wfU[mat][ks] = *(const f16x8*)(Uiou16 +
                (mat * 256 + wcol + l15) * HDIM + ks * 32 + qk);
    const float bi  = b_iou[wcol + l15];
    const float bo  = b_iou[256 + wcol + l15];
    const float bu  = b_iou[512 + wcol + l15];
    const float bfv = b_f[wcol + l15];

    const int p0 = blockIdx.x * chunk;              // chunk divides rows_p

    for (int pt = 0; pt < chunk / 16; ++pt) {
        const int pw = p0 + pt * 16;                // tile's first parent
        const int cw = 2 * pw;                      // first child row

        // ---------------- Phase 1: forget gates on 32 children ------------
        int childBase[2];
        #pragma unroll
        for (int rf = 0; rf < 2; ++rf) {
            int cl = cw + rf * 16 + l15;
            childBase[rf] = ((cl >> lc) * M_NODES + maskc + (cl & maskc)) * HDIM;
        }
        f32x4 accf[2] = {};
        #pragma unroll
        for (int ks = 0; ks < 8; ++ks) {
            const int k0 = ks * 32 + qk;
            f16x8 a0 = *(const f16x8*)(h16 + childBase[0] + k0);
            f16x8 a1 = *(const f16x8*)(h16 + childBase[1] + k0);
            accf[0] = __builtin_amdgcn_mfma_f32_16x16x32_f16(a0, wfF[ks], accf[0], 0, 0, 0);
            accf[1] = __builtin_amdgcn_mfma_f32_16x16x32_f16(a1, wfF[ks], accf[1], 0, 0, 0);
        }
        f16x4 cc[2];
        #pragma unroll
        for (int rf = 0; rf < 2; ++rf)
            cc[rf] = *(const f16x4*)(cT_child +
                (wcol + l15) * rows_c + cw + rf * 16 + quad * 4);
        #pragma unroll
        for (int rf = 0; rf < 2; ++rf)
            #pragma unroll
            for (int pr = 0; pr < 2; ++pr) {
                float f0 = sigf(accf[rf][2 * pr]     + bfv);
                float f1 = sigf(accf[rf][2 * pr + 1] + bfv);
                float fc = f0 * (float)cc[rf][2 * pr]
                         + f1 * (float)cc[rf][2 * pr + 1];
                fcs[w][(rf * 8 + quad * 2 + pr) * FCS_S + l15] = fc;
            }

        // ---------------- Phase 2: iou GEMM on child-sum h ----------------
        int pcBase;
        {
            int p = pw + l15;
            int b = p >> l, t = p & maskp;
            pcBase = (b * M_NODES + (2 << l) - 1 + 2 * t) * HDIM;
        }
        f32x4 acc[3] = {};
        #pragma unroll
        for (int ks = 0; ks < 8; ++ks) {
            const int k0 = ks * 32 + qk;
            f16x8 a1 = *(const f16x8*)(h16 + pcBase + k0);
            f16x8 a2 = *(const f16x8*)(h16 + pcBase + HDIM + k0);
            f16x8 av = a1 + a2;                     // child-sum of h
            #pragma unroll
            for (int mat = 0; mat < 3; ++mat)
                acc[mat] = __builtin_amdgcn_mfma_f32_16x16x32_f16(
                    av, wfU[mat][ks], acc[mat], 0, 0, 0);
        }

        f16x4 cv;
        #pragma unroll
        for (int r = 0; r < 4; ++r) {
            float fcv = fcs[w][(quad * 4 + r) * FCS_S + l15];
            float i_ = acc[0][r] + bi;
            float o_ = acc[1][r] + bo;
            float u_ = acc[2][r] + bu;
            float c  = sigf(i_) * tanh_fast(u_) + fcv;
            float h  = sigf(o_) * tanh_fast(c);
            cv[r] = (f16)c;
            ldsh[w][(quad * 4 + r) * LDSH_S + l15] = (f16)h;
        }
        *(f16x4*)(cT_parent + (wcol + l15) * rows_p + pw + quad * 4) = cv;

        // Wave-local drain of h tile
        {
            int row_l = lane >> 2, cpos = (lane & 3) * 4;
            int p  = pw + row_l;
            int b  = p >> l, tt = p & maskp;
            int node = b * M_NODES + (1 << l) - 1 + tt;
            f16x4 v = *(const f16x4*)(&ldsh[w][row_l * LDSH_S + cpos]);
            *(f16x4*)(h16 + node * HDIM + wcol + cpos) = v;
        }
    }
}

// ---------------------------------------------------------------------------
// Output: out = h_all @ W_out^T + b_out (N padded 20->32). Persistent
// weights (64 VGPRs). Block = 16 tiles of 16 rows; wave handles tiles
// w, w+4, ... N_NODES = 16*8190 exactly (no row remainder).
// ---------------------------------------------------------------------------
__global__ __launch_bounds__(256, 2) void out_kernel(
    const f16* __restrict__ h16, const f16* __restrict__ Wout16,
    const float* __restrict__ bout, float* __restrict__ out)
{
    const int lane = threadIdx.x & 63;
    const int w    = threadIdx.x >> 6;
    const int quad = lane >> 4;
    const int l15  = lane & 15;
    const int qk   = quad * 8;

    f16x8 wf[2];
    #pragma unroll
    for (int cf = 0; cf < 2; ++cf)
        wf[cf] = *(const f16x8*)(Wout16 + (cf * 16 + l15) * HDIM + qk);
    // full K in 8 frags per cf
    f16x8 wfk[2][8];
    #pragma unroll
    for (int cf = 0; cf < 2; ++cf)
        #pragma unroll
        for (int ks = 0; ks < 8; ++ks)
            wfk[cf][ks] = *(const f16x8*)(Wout16 +
                (cf * 16 + l15) * HDIM + ks * 32 + qk);
    float bo[2];
    #pragma unroll
    for (int cf = 0; cf < 2; ++cf) {
        int col = cf * 16 + l15;
        bo[cf] = bout[col < NCLS ? col : 0];
    }

    const int tile0   = blockIdx.x * 16;
    const int ntotal  = N_NODES / 16;               // 8190
    const int tend    = (tile0 + 16 < ntotal) ? 16 : (ntotal - tile0);

    for (int rt = w; rt < tend; rt += 4) {
        const int rw = (tile0 + rt) * 16;
        f32x4 acc[2] = {};
        #pragma unroll
        for (int ks = 0; ks < 8; ++ks) {
            f16x8 a = *(const f16x8*)(h16 + (rw + l15) * HDIM + ks * 32 + qk);
            #pragma unroll
            for (int cf = 0; cf < 2; ++cf)
                acc[cf] = __builtin_amdgcn_mfma_f32_16x16x32_f16(
                    a, wfk[cf][ks], acc[cf], 0, 0, 0);
        }
        #pragma unroll
        for (int cf = 0; cf < 2; ++cf) {
            const int col = cf * 16 + l15;
            if (col < NCLS) {
                #pragma unroll
                for (int r = 0; r < 4; ++r)
                    out[(rw + quad * 4 + r) * NCLS + col] = acc[cf][r] + bo[cf];
            }
        }
    }
}

// ---------------------------------------------------------------------------
extern "C" void kernel_launch(void* const* d_in, const int* in_sizes, int n_in,
                              void* d_out, int out_size, void* d_ws, size_t ws_size,
                              hipStream_t stream)
{
    const int*   x     = (const int*)d_in[0];
    // d_in[1] = x_mask: leaf structure is static — folded into indexing.
    const float* Emb   = (const float*)d_in[2];
    const float* W_iou = (const float*)d_in[3];
    const float* b_iou = (const float*)d_in[4];
    const float* U_iou = (const float*)d_in[5];
    const float* U_f   = (const float*)d_in[6];
    const float* b_f   = (const float*)d_in[7];
    const float* W_out = (const float*)d_in[8];
    const float* b_out = (const float*)d_in[9];
    float* out = (float*)d_out;

    // Workspace: h16 67.1 + cA 33.6 + cB 16.8 + Emb16 16.4 + weights ~1 MB
    char* ws = (char*)d_ws;
    size_t off = 0;
    auto take = [&](size_t bytes) -> char* {
        char* p = ws + off; off += (bytes + 255) & ~(size_t)255; return p;
    };
    f16* h16    = (f16*)take((size_t)N_NODES * HDIM * 2);
    f16* cA     = (f16*)take((size_t)HDIM * LEAFROWS * 2);        // [256][65536]
    f16* cB     = (f16*)take((size_t)HDIM * (LEAFROWS / 2) * 2);  // [256][32768]
    f16* Emb16  = (f16*)take((size_t)VOCAB * HDIM * 2);
    f16* Wiou16 = (f16*)take((size_t)768 * HDIM * 2);
    f16* Uiou16 = (f16*)take((size_t)768 * HDIM * 2);
    f16* Uf16   = (f16*)take((size_t)HDIM * HDIM * 2);
    f16* Wout16 = (f16*)take((size_t)32 * HDIM * 2);

    cvt_kernel<<<VOCAB * HDIM / 4 / 256, 256, 0, stream>>>(
        (const float4*)Emb, (const float4*)W_iou, (const float4*)U_iou,
        (const float4*)U_f, (const float4*)W_out,
        (f16x4*)Emb16, (f16x4*)Wiou16, (f16x4*)Uiou16, (f16x4*)Uf16,
        (f16x4*)Wout16);

    // Leaves: grid (256, 4), 256 rows x 64 cols per block
    leaf_kernel<<<dim3(LEAFROWS / LEAF_CHUNK, 4), 256, 0, stream>>>(
        x, Emb16, Wiou16, b_iou, h16, cA);

    // Levels 10..0, fused fgate+level, ping-pong transposed c buffers
    f16* cin  = cA;
    f16* cout_ = cB;
    for (int l = 10; l >= 0; --l) {
        int rows_p = B_TREES << l;
        int chunk  = rows_p >> 8; if (chunk < 16) chunk = 16;
        fused_level_kernel<<<dim3(rows_p / chunk, 4), 256, 0, stream>>>(
            Uiou16, Uf16, b_iou, b_f, h16, cin, cout_, l, rows_p, chunk);
        f16* t = cin; cin = cout_; cout_ = t;
    }

    out_kernel<<<dim3((N_NODES / 16 + 15) / 16), 256, 0, stream>>>(
        h16, Wout16, b_out, out);
}

// Round 7
// 410.370 us; speedup vs baseline: 1.9468x; 1.3752x over previous
//
#include <hip/hip_runtime.h>

// Problem constants (from reference)
#define B_TREES 32
#define DEPTH   12
#define M_NODES 4095                  // 2^12 - 1
#define N_NODES (B_TREES * M_NODES)   // 131040
#define HDIM    256
#define VOCAB   32000
#define NCLS    20
#define LEAFROWS 65536                // 32 * 2048 leaves
#define LDSH_S 20                     // padded stride of 16x16 h transpose tile

typedef _Float16 f16;
typedef _Float16 f16x8 __attribute__((ext_vector_type(8)));
typedef _Float16 f16x4 __attribute__((ext_vector_type(4)));
typedef _Float16 f16x2 __attribute__((ext_vector_type(2)));
typedef float    f32x4 __attribute__((ext_vector_type(4)));

__device__ __forceinline__ float sigf(float x)      { return 1.0f / (1.0f + __expf(-x)); }
__device__ __forceinline__ float tanh_fast(float x) { return 1.0f - 2.0f / (1.0f + __expf(2.0f * x)); }

// ---------------------------------------------------------------------------
// Init: convert Emb + weights to fp16. W_out padded to 32 rows (zeros).
// ---------------------------------------------------------------------------
__global__ __launch_bounds__(256) void cvt_kernel(
    const float4* __restrict__ Emb,  const float4* __restrict__ Wiou,
    const float4* __restrict__ Uiou, const float4* __restrict__ Uf,
    const float4* __restrict__ Wout,
    f16x4* __restrict__ Emb16,  f16x4* __restrict__ Wiou16,
    f16x4* __restrict__ Uiou16, f16x4* __restrict__ Uf16,
    f16x4* __restrict__ Wout16)
{
    int i = blockIdx.x * 256 + threadIdx.x;   // in units of 4 floats
    if (i < VOCAB * HDIM / 4) {
        float4 v = Emb[i];
        f16x4 r; r[0] = (f16)v.x; r[1] = (f16)v.y; r[2] = (f16)v.z; r[3] = (f16)v.w;
        Emb16[i] = r;
    }
    if (i < 768 * HDIM / 4) {
        float4 v = Wiou[i];
        f16x4 r; r[0] = (f16)v.x; r[1] = (f16)v.y; r[2] = (f16)v.z; r[3] = (f16)v.w;
        Wiou16[i] = r;
        float4 u = Uiou[i];
        f16x4 s; s[0] = (f16)u.x; s[1] = (f16)u.y; s[2] = (f16)u.z; s[3] = (f16)u.w;
        Uiou16[i] = s;
    }
    if (i < HDIM * HDIM / 4) {
        float4 v = Uf[i];
        f16x4 r; r[0] = (f16)v.x; r[1] = (f16)v.y; r[2] = (f16)v.z; r[3] = (f16)v.w;
        Uf16[i] = r;
    }
    if (i < 32 * HDIM / 4) {                  // 32 padded rows of W_out
        int row = i >> 6;
        f16x4 r = {};
        if (row < NCLS) {
            float4 v = Wout[i];
            r[0] = (f16)v.x; r[1] = (f16)v.y; r[2] = (f16)v.z; r[3] = (f16)v.w;
        }
        Wout16[i] = r;
    }
}

// ---------------------------------------------------------------------------
// Leaf kernel: block owns 16 output cols; Wiou 16-col tile (3 gates, 24 KB)
// staged in LDS in MFMA-fragment order. Each wave loops 8 row-tiles of 16
// leaves with 1-deep A-prefetch. Grid (128, 16).
// ---------------------------------------------------------------------------
#define LEAF_TPW 8
__global__ __launch_bounds__(256) void leaf_kernel(
    const int* __restrict__ x, const f16* __restrict__ Emb16,
    const f16* __restrict__ Wiou16, const float* __restrict__ b_iou,
    f16* __restrict__ h16, f16* __restrict__ cT)
{
    __shared__ f16 wlds[1536 * 8];             // 24 KB: [mat][ks][quad][col] 16B frags
    __shared__ f16 ldsh[4][16 * LDSH_S];

    const int tid  = threadIdx.x;
    const int lane = tid & 63;
    const int w    = tid >> 6;
    const int quad = lane >> 4;
    const int l15  = lane & 15;
    const int qk   = quad * 8;
    const int cb0  = blockIdx.y * 16;          // block's 16 cols

    // Stage weights (frag f = mat*512 + ks*64 + quad*16 + col)
    #pragma unroll
    for (int i = 0; i < 6; ++i) {
        int f = i * 256 + tid;
        int mat = f >> 9, r = f & 511, ks = r >> 6, q = (r >> 4) & 3, c = r & 15;
        *(f16x8*)(wlds + f * 8) = *(const f16x8*)(Wiou16 +
            (mat * 256 + cb0 + c) * HDIM + ks * 32 + q * 8);
    }
    __syncthreads();

    const float bi = b_iou[cb0 + l15];
    const float bo = b_iou[256 + cb0 + l15];
    const float bu = b_iou[512 + cb0 + l15];

    const int row0 = (blockIdx.x * 4 + w) * (LEAF_TPW * 16);  // wave's rows

    // Prefetch tile 0 (16 leaf rows are node-contiguous: 16 | 2048)
    int nodeRow = (row0 >> 11) * M_NODES + 2047 + (row0 & 2047);
    int embBase = x[nodeRow + l15] * HDIM;
    f16x8 a[8];
    #pragma unroll
    for (int ks = 0; ks < 8; ++ks)
        a[ks] = *(const f16x8*)(Emb16 + embBase + ks * 32 + qk);

    for (int rt = 0; rt < LEAF_TPW; ++rt) {
        const int rw = row0 + rt * 16;
        const int curNode = nodeRow;
        f16x8 ac[8];
        #pragma unroll
        for (int ks = 0; ks < 8; ++ks) ac[ks] = a[ks];

        if (rt + 1 < LEAF_TPW) {               // prefetch next tile
            const int rwn = rw + 16;
            nodeRow = (rwn >> 11) * M_NODES + 2047 + (rwn & 2047);
            embBase = x[nodeRow + l15] * HDIM;
            #pragma unroll
            for (int ks = 0; ks < 8; ++ks)
                a[ks] = *(const f16x8*)(Emb16 + embBase + ks * 32 + qk);
        }

        f32x4 acc[3] = {};
        #pragma unroll
        for (int ks = 0; ks < 8; ++ks) {
            #pragma unroll
            for (int mat = 0; mat < 3; ++mat) {
                f16x8 wf = *(const f16x8*)(wlds +
                    ((mat * 8 + ks) * 64 + quad * 16 + l15) * 8);
                acc[mat] = __builtin_amdgcn_mfma_f32_16x16x32_f16(
                    ac[ks], wf, acc[mat], 0, 0, 0);
            }
        }

        // Epilogue (leaves: h_sum = fc_sum = 0)
        f16x4 cv;
        #pragma unroll
        for (int r = 0; r < 4; ++r) {
            float i_ = acc[0][r] + bi;
            float o_ = acc[1][r] + bo;
            float u_ = acc[2][r] + bu;
            float c  = sigf(i_) * tanh_fast(u_);
            float h  = sigf(o_) * tanh_fast(c);
            cv[r] = (f16)c;
            ldsh[w][(quad * 4 + r) * LDSH_S + l15] = (f16)h;
        }
        *(f16x4*)(cT + (cb0 + l15) * LEAFROWS + rw + quad * 4) = cv;

        // Wave-local drain of 16x16 h tile (8B stores)
        {
            int row_l = lane >> 2, cpos = (lane & 3) * 4;
            f16x4 v = *(const f16x4*)(&ldsh[w][row_l * LDSH_S + cpos]);
            *(f16x4*)(h16 + (curNode + row_l) * HDIM + cb0 + cpos) = v;
        }
    }
}

// ---------------------------------------------------------------------------
// Fused level kernel: block owns 16 cols; Uf + Uiou 16-col tiles (32 KB) in
// LDS. Single K-loop per 16-parent tile reads the 32 child-h rows ONCE:
//   accf{0,1}  = child_h @ Uf^T          (forget-gate pre-activations)
//   au{0,1}[m] = child_h @ Uiou[m]^T     (iou on CHILD rows)
// Parent iou = in-lane pair-sum of adjacent child-row outputs (C/D rows
// (2j,2j+1) are adjacent regs of the same lane). fc = f0*c0+f1*c1 in-lane.
// No fcs LDS, no second h read, no block barrier after staging.
// ---------------------------------------------------------------------------
__global__ __launch_bounds__(256) void fused_level_kernel(
    const f16* __restrict__ Uiou16, const f16* __restrict__ Uf16,
    const float* __restrict__ b_iou, const float* __restrict__ b_f,
    f16* __restrict__ h16, const f16* __restrict__ cT_child,
    f16* __restrict__ cT_parent, int l, int rows_p, int tpw)
{
    __shared__ f16 wlds[2048 * 8];             // 32 KB: mat0=Uf, mat1..3=Uiou
    __shared__ f16 ldsh[4][16 * LDSH_S];

    const int tid  = threadIdx.x;
    const int lane = tid & 63;
    const int w    = tid >> 6;
    const int quad = lane >> 4;
    const int l15  = lane & 15;
    const int qk   = quad * 8;
    const int cb0  = blockIdx.y * 16;

    // Stage weights
    #pragma unroll
    for (int i = 0; i < 8; ++i) {
        int f = i * 256 + tid;
        int mat = f >> 9, r = f & 511, ks = r >> 6, q = (r >> 4) & 3, c = r & 15;
        const f16* src = (mat == 0)
            ? (Uf16 + (cb0 + c) * HDIM + ks * 32 + q * 8)
            : (Uiou16 + ((mat - 1) * 256 + cb0 + c) * HDIM + ks * 32 + q * 8);
        *(f16x8*)(wlds + f * 8) = *(const f16x8*)src;
    }
    __syncthreads();

    const float bi  = b_iou[cb0 + l15];
    const float bo  = b_iou[256 + cb0 + l15];
    const float bu  = b_iou[512 + cb0 + l15];
    const float bfv = b_f[cb0 + l15];
    const int lc = l + 1;
    const int maskc = (1 << lc) - 1;
    const int maskp = (1 << l) - 1;
    const int rows_c = rows_p * 2;

    const int p0 = blockIdx.x * (tpw * 64);

    for (int pt = 0; pt < tpw; ++pt) {
        const int pw = p0 + (pt * 4 + w) * 16;   // tile's first parent
        if (pw >= rows_p) continue;
        const int cw = 2 * pw;

        int childBase0, childBase1;
        {
            int cl0 = cw + l15;
            childBase0 = ((cl0 >> lc) * M_NODES + maskc + (cl0 & maskc)) * HDIM;
            int cl1 = cw + 16 + l15;
            childBase1 = ((cl1 >> lc) * M_NODES + maskc + (cl1 & maskc)) * HDIM;
        }

        f32x4 accf0 = {}, accf1 = {};
        f32x4 au0[3] = {}, au1[3] = {};
        #pragma unroll
        for (int ks = 0; ks < 8; ++ks) {
            const int k0 = ks * 32 + qk;
            f16x8 a0 = *(const f16x8*)(h16 + childBase0 + k0);
            f16x8 a1 = *(const f16x8*)(h16 + childBase1 + k0);
            f16x8 wfF = *(const f16x8*)(wlds + (ks * 64 + quad * 16 + l15) * 8);
            accf0 = __builtin_amdgcn_mfma_f32_16x16x32_f16(a0, wfF, accf0, 0, 0, 0);
            accf1 = __builtin_amdgcn_mfma_f32_16x16x32_f16(a1, wfF, accf1, 0, 0, 0);
            #pragma unroll
            for (int m = 0; m < 3; ++m) {
                f16x8 wm = *(const f16x8*)(wlds +
                    (((m + 1) * 8 + ks) * 64 + quad * 16 + l15) * 8);
                au0[m] = __builtin_amdgcn_mfma_f32_16x16x32_f16(a0, wm, au0[m], 0, 0, 0);
                au1[m] = __builtin_amdgcn_mfma_f32_16x16x32_f16(a1, wm, au1[m], 0, 0, 0);
            }
        }

        // Epilogue: two child sets -> parents pw..pw+7 and pw+8..pw+15
        #pragma unroll
        for (int s = 0; s < 2; ++s) {
            const f32x4& af = s ? accf1 : accf0;
            const f32x4* au = s ? au1 : au0;
            const int csr = cw + s * 16;          // child rows of this set
            f16x4 cc = *(const f16x4*)(cT_child +
                (cb0 + l15) * rows_c + csr + quad * 4);
            f16x2 cpack;
            #pragma unroll
            for (int pr = 0; pr < 2; ++pr) {
                float f0 = sigf(af[2 * pr]     + bfv);
                float f1 = sigf(af[2 * pr + 1] + bfv);
                float fc = f0 * (float)cc[2 * pr] + f1 * (float)cc[2 * pr + 1];
                float i_ = au[0][2 * pr] + au[0][2 * pr + 1] + bi;
                float o_ = au[1][2 * pr] + au[1][2 * pr + 1] + bo;
                float u_ = au[2][2 * pr] + au[2][2 * pr + 1] + bu;
                float c  = sigf(i_) * tanh_fast(u_) + fc;
                float h  = sigf(o_) * tanh_fast(c);
                cpack[pr] = (f16)c;
                ldsh[w][(s * 8 + quad * 2 + pr) * LDSH_S + l15] = (f16)h;
            }
            *(f16x2*)(cT_parent + (cb0 + l15) * rows_p + pw + s * 8 + quad * 2) = cpack;
        }

        // Wave-local drain of 16-parent x 16-col h tile (8B stores)
        {
            int prow = lane >> 2, cpos = (lane & 3) * 4;
            int p = pw + prow;
            int b = p >> l, tt = p & maskp;
            int node = b * M_NODES + (1 << l) - 1 + tt;
            f16x4 v = *(const f16x4*)(&ldsh[w][prow * LDSH_S + cpos]);
            *(f16x4*)(h16 + node * HDIM + cb0 + cpos) = v;
        }
    }
}

// ---------------------------------------------------------------------------
// Output: out = h_all @ W_out^T + b_out (N padded 20->32). Persistent
// weights (64 VGPRs). N_NODES = 16*8190 exactly.
// ---------------------------------------------------------------------------
__global__ __launch_bounds__(256) void out_kernel(
    const f16* __restrict__ h16, const f16* __restrict__ Wout16,
    const float* __restrict__ bout, float* __restrict__ out)
{
    const int lane = threadIdx.x & 63;
    const int w    = threadIdx.x >> 6;
    const int quad = lane >> 4;
    const int l15  = lane & 15;
    const int qk   = quad * 8;

    f16x8 wfk[2][8];
    #pragma unroll
    for (int cf = 0; cf < 2; ++cf)
        #pragma unroll
        for (int ks = 0; ks < 8; ++ks)
            wfk[cf][ks] = *(const f16x8*)(Wout16 +
                (cf * 16 + l15) * HDIM + ks * 32 + qk);
    float bo[2];
    #pragma unroll
    for (int cf = 0; cf < 2; ++cf) {
        int col = cf * 16 + l15;
        bo[cf] = bout[col < NCLS ? col : 0];
    }

    const int tile0  = blockIdx.x * 16;
    const int ntotal = N_NODES / 16;               // 8190
    const int tend   = (tile0 + 16 < ntotal) ? 16 : (ntotal - tile0);

    for (int rt = w; rt < tend; rt += 4) {
        const int rw = (tile0 + rt) * 16;
        f32x4 acc[2] = {};
        #pragma unroll
        for (int ks = 0; ks < 8; ++ks) {
            f16x8 a = *(const f16x8*)(h16 + (rw + l15) * HDIM + ks * 32 + qk);
            #pragma unroll
            for (int cf = 0; cf < 2; ++cf)
                acc[cf] = __builtin_amdgcn_mfma_f32_16x16x32_f16(
                    a, wfk[cf][ks], acc[cf], 0, 0, 0);
        }
        #pragma unroll
        for (int cf = 0; cf < 2; ++cf) {
            const int col = cf * 16 + l15;
            if (col < NCLS) {
                #pragma unroll
                for (int r = 0; r < 4; ++r)
                    out[(rw + quad * 4 + r) * NCLS + col] = acc[cf][r] + bo[cf];
            }
        }
    }
}

// ---------------------------------------------------------------------------
extern "C" void kernel_launch(void* const* d_in, const int* in_sizes, int n_in,
                              void* d_out, int out_size, void* d_ws, size_t ws_size,
                              hipStream_t stream)
{
    const int*   x     = (const int*)d_in[0];
    // d_in[1] = x_mask: leaf structure is static — folded into indexing.
    const float* Emb   = (const float*)d_in[2];
    const float* W_iou = (const float*)d_in[3];
    const float* b_iou = (const float*)d_in[4];
    const float* U_iou = (const float*)d_in[5];
    const float* U_f   = (const float*)d_in[6];
    const float* b_f   = (const float*)d_in[7];
    const float* W_out = (const float*)d_in[8];
    const float* b_out = (const float*)d_in[9];
    float* out = (float*)d_out;

    char* ws = (char*)d_ws;
    size_t off = 0;
    auto take = [&](size_t bytes) -> char* {
        char* p = ws + off; off += (bytes + 255) & ~(size_t)255; return p;
    };
    f16* h16    = (f16*)take((size_t)N_NODES * HDIM * 2);
    f16* cA     = (f16*)take((size_t)HDIM * LEAFROWS * 2);        // [256][65536]
    f16* cB     = (f16*)take((size_t)HDIM * (LEAFROWS / 2) * 2);  // [256][32768]
    f16* Emb16  = (f16*)take((size_t)VOCAB * HDIM * 2);
    f16* Wiou16 = (f16*)take((size_t)768 * HDIM * 2);
    f16* Uiou16 = (f16*)take((size_t)768 * HDIM * 2);
    f16* Uf16   = (f16*)take((size_t)HDIM * HDIM * 2);
    f16* Wout16 = (f16*)take((size_t)32 * HDIM * 2);

    cvt_kernel<<<VOCAB * HDIM / 4 / 256, 256, 0, stream>>>(
        (const float4*)Emb, (const float4*)W_iou, (const float4*)U_iou,
        (const float4*)U_f, (const float4*)W_out,
        (f16x4*)Emb16, (f16x4*)Wiou16, (f16x4*)Uiou16, (f16x4*)Uf16,
        (f16x4*)Wout16);

    // Leaves: grid (128, 16); block = 16 cols x 512 rows (8 tiles/wave)
    leaf_kernel<<<dim3(LEAFROWS / (4 * 16 * LEAF_TPW), 16), 256, 0, stream>>>(
        x, Emb16, Wiou16, b_iou, h16, cA);

    // Levels 10..0, fused fgate+iou, ping-pong transposed c buffers
    f16* cin  = cA;
    f16* cout_ = cB;
    for (int l = 10; l >= 0; --l) {
        int rows_p = B_TREES << l;
        int tpw = rows_p / (64 * 128); if (tpw < 1) tpw = 1;
        int gx  = (rows_p + tpw * 64 - 1) / (tpw * 64);
        fused_level_kernel<<<dim3(gx, 16), 256, 0, stream>>>(
            Uiou16, Uf16, b_iou, b_f, h16, cin, cout_, l, rows_p, tpw);
        f16* t = cin; cin = cout_; cout_ = t;
    }

    out_kernel<<<dim3((N_NODES / 16 + 15) / 16), 256, 0, stream>>>(
        h16, Wout16, b_out, out);
}